// Round 6
// baseline (89.923 us; speedup 1.0000x reference)
//
#include <hip/hip_runtime.h>
#include <math.h>

// R19 DIAGNOSTIC: R17 kernel (best: 67.14us) + 3 extra warm gather passes.
// Purpose: (1) dur delta / 3 = marginal warm gather mem-path time;
// (2) push the kernel's duration past the 41us poison-fill so it enters the
// rocprof top-5 and we finally see ITS counters (VALUBusy/FETCH/Occupancy/
// LDS-conflict) instead of the fill's. Output math untouched -> still passes.
// Extra-pass loads are kept live via asm-consume (no DCE) and use per-pass
// opaque-zero address offsets (volatile v_mov) so passes can't CSE.
//
//   vol: (B=1, C=1, W=96, H=96, D=64) float32 -> vol[(x*96+y)*64+z]
//   out: (B,C,U=96,A=90,V=64) float32 -> out[(u*90+a)*64+v]
namespace {
constexpr int NA = 90, NU = 96, NV = 64, NW = 96, NH = 96, ND = 64;
constexpr int NRAY   = NA * NU;      // 8640
constexpr int NENT   = 256;          // entries per ray (<=4 rounds x 64 lanes)
constexpr int CNTMAX = 208;          // gather cap (valid count <= ~196 structurally)
constexpr int TILE   = 8;            // rays per block = waves per block
constexpr int NBLK   = 1024;         // exactly 4 blocks/CU (32 waves/CU), vgpr<=64
constexpr int NEXTRA = NRAY - NBLK * TILE;  // 448 leftover rays, spread 1-per-block
}

// Compact branch-free f64 sincos (fdlibm kernel polys, |err| ~3e-16).
__device__ inline void sincos_poly(double xd, float* s, float* c)
{
    const double INV_PIO2 = 0.63661977236758134308;
    const double PIO2_HI  = 1.57079632679489655800e+00;
    const double PIO2_LO  = 6.12323399573676603587e-17;
    const double qd = rint(xd * INV_PIO2);            // 0,1,2 for xd in [0, 3.11)
    const double r  = (xd - qd * PIO2_HI) - qd * PIO2_LO;
    const double z  = r * r;
    const double sp = r + (r * z) * (-1.66666666666666324348e-01 + z *
                     ( 8.33333333332248946124e-03 + z *
                     (-1.98412698298579493134e-04 + z *
                     ( 2.75573137070700676789e-06 + z *
                     (-2.50507602534068634195e-08 + z *
                       1.58969099521155010221e-10)))));
    const double cp = 1.0 + z * (-0.5 + z *
                     ( 4.16666666666666019037e-02 + z *
                     (-1.38888888888741095749e-03 + z *
                     ( 2.48015872894767294178e-05 + z *
                     (-2.75573143513906633035e-07 + z *
                     ( 2.08757232129817482790e-09 + z *
                      -1.13596475577881948265e-11))))));
    const int q = (int)qd;
    const double sv = (q == 0) ? sp : ((q == 1) ? cp : -sp);
    const double cv = (q == 0) ? cp : ((q == 1) ? -sp : -cp);
    *s = (float)sv;
    *c = (float)cv;
}

// Wave-uniform scalars -> SGPRs (R16; semantics-preserving, all lanes identical).
__device__ __forceinline__ float rflf(float x) {
    return __int_as_float(__builtin_amdgcn_readfirstlane(__float_as_int(x)));
}
__device__ __forceinline__ int rfli(int x) {
    return __builtin_amdgcn_readfirstlane(x);
}

// One full ray (setup -> trace -> gather [+3 diag passes] -> out write).
__device__ __forceinline__ void do_ray(const float* __restrict__ vol,
                                       float* __restrict__ out,
                                       int2* __restrict__ myRow,
                                       const int ray, const int lane)
{
    const int a = ray / NU;
    const int u = ray - a * NU;

    const float EPSf = 1e-12f;
    const float INFp = __builtin_inff();
    const float DIAG = 1.41421356237309514547f;

    // ---------------- per-ray setup (wave-uniform) ----------------
    const float ang = (float)a * (float)(3.14159265358979323846 / 90.0);
    float dy, dx;
    sincos_poly((double)ang, &dy, &dx);        // dx = cos, dy = sin (f32-exact)
    const float uu = (float)u - 47.5f;
    const float x0 = __fmul_rn(-uu, dy);
    const float y0 = __fmul_rn( uu, dx);

    const float xmin = -47.5f, xmax = 47.5f;
    const float ymin = -47.5f, ymax = 47.5f;

    float tx0, tx1;
    {
        const bool par = fabsf(dx) < EPSf;
        const float safe = par ? 1.0f : dx;
        const float t0 = __fdiv_rn(xmin - x0, safe);
        const float t1 = __fdiv_rn(xmax - x0, safe);
        const float lo = fminf(t0, t1), hi = fmaxf(t0, t1);
        const bool inside = (x0 >= xmin) && (x0 <= xmax);
        tx0 = par ? (inside ? -INFp : INFp) : lo;
        tx1 = par ? (inside ?  INFp : -INFp) : hi;
    }
    float ty0, ty1;
    {
        const bool par = fabsf(dy) < EPSf;
        const float safe = par ? 1.0f : dy;
        const float t0 = __fdiv_rn(ymin - y0, safe);
        const float t1 = __fdiv_rn(ymax - y0, safe);
        const float lo = fminf(t0, t1), hi = fmaxf(t0, t1);
        const bool inside = (y0 >= ymin) && (y0 <= ymax);
        ty0 = par ? (inside ? -INFp : INFp) : lo;
        ty1 = par ? (inside ?  INFp : -INFp) : hi;
    }

    const float t_entry = fmaxf(tx0, ty0);
    const float t_exit  = fminf(tx1, ty1);
    const bool  alive0  = t_entry < t_exit;
    const float te  = rflf(alive0 ? t_entry : 0.0f);
    const float tex = rflf(alive0 ? t_exit  : 0.0f);

    const float xe = __fadd_rn(x0, __fmul_rn(te, dx));
    const float ye = __fadd_rn(y0, __fmul_rn(te, dy));
    const int i0 = rfli((int)fminf(fmaxf(rintf(__fadd_rn(xe, 47.5f)), 0.0f), 95.0f));
    const int j0 = rfli((int)fminf(fmaxf(rintf(__fadd_rn(ye, 47.5f)), 0.0f), 95.0f));

    const bool okx = fabsf(dx) > EPSf;
    const bool oky = fabsf(dy) > EPSf;
    const float inv_dx = okx ? __fdiv_rn(1.0f, dx) : 0.0f;
    const float inv_dy = oky ? __fdiv_rn(1.0f, dy) : 0.0f;
    const float wscale = rflf(__fdiv_rn(DIAG, fmaxf(fabsf(dx) + fabsf(dy), EPSf)));
    // When !alive0: te=tex=0 => prev >= 0 > tex-eps => inactive automatically.
    const float tex_m_eps = rflf(__fadd_rn(tex, -EPSf));

    // APs of crossing times: Tx_k = Ax + k*px, Ty_m = Ay + m*py (absolute t).
    const float cx = (dx > 0.0f) ? -47.0f : -48.0f;
    const float cy = (dy > 0.0f) ? -47.0f : -48.0f;
    const float Ax = rflf(okx ? __fadd_rn(te, __fmul_rn(((float)i0 + cx) - xe, inv_dx)) : INFp);
    const float Ay = rflf(oky ? __fadd_rn(te, __fmul_rn(((float)j0 + cy) - ye, inv_dy)) : INFp);
    const float px = rflf(okx ? fabsf(inv_dx) : 0.0f);
    const float py = rflf(oky ? fabsf(inv_dy) : 0.0f);
    const int   si = rfli((dx > 0.0f) ? 1 : -1);
    const int   sj = rfli((dy > 0.0f) ? 1 : -1);

    const float inv_pq = rflf(__fdiv_rn(1.0f, px + py));
    const float Cc = rflf(Ay - Ax);

    // ---- R17: closed-form valid-segment count -> variable round count ----
    int nx = 0, ny = 0;
    if (okx) {
        const float Qx = __fdiv_rn(tex_m_eps - Ax, px);
        nx = min(96, max(0, (int)floorf(Qx) + 1));
    }
    if (oky) {
        const float Qy = __fdiv_rn(tex_m_eps - Ay, py);
        ny = min(96, max(0, (int)floorf(Qy) + 1));
    }
    const int nvalid = 1 + nx + ny;                     // <= 193 structurally
    const int rounds = rfli(alive0 ? min(4, (nvalid + 2 + 63) >> 6) : 0);

    // ---------------- lane-parallel trace: `rounds` rounds of 64 entries ----
    int cnt = 0;
    for (int rnd = 0; rnd < rounds; ++rnd) {
        const int n = (rnd << 6) + lane;
        const float nf = (float)n;

        float kf = __fmul_rn(__fmaf_rn(nf, py, Cc), inv_pq);
        kf = fminf(fmaxf(kf, 0.0f), nf);       // also collapses +-INF safely
        int k = (int)rintf(kf);

        // partition fixup: valid iff Tx_{k-1} <= Ty_{n-k} and Ty_{n-k-1} <= Tx_k.
        #pragma unroll
        for (int it = 0; it < 4; ++it) {
            const int m = n - k;
            const float Txk   = __fmaf_rn((float)k, px, Ax);
            const float Txkm1 = (k > 0) ? __fmaf_rn((float)(k - 1), px, Ax) : -INFp;
            const float Tyl   = __fmaf_rn((float)m, py, Ay);
            const float Tylm1 = (m > 0) ? __fmaf_rn((float)(m - 1), py, Ay) : -INFp;
            const bool dec = (Txkm1 > Tyl);
            const bool inc = (!dec) && (Tylm1 > Txk);
            k += inc ? 1 : (dec ? -1 : 0);
        }

        const int m = n - k;
        const float Txk   = __fmaf_rn((float)k, px, Ax);
        const float Txkm1 = (k > 0) ? __fmaf_rn((float)(k - 1), px, Ax) : -INFp;
        const float Tyl   = __fmaf_rn((float)m, py, Ay);
        const float Tylm1 = (m > 0) ? __fmaf_rn((float)(m - 1), py, Ay) : -INFp;

        const float Tn   = fminf(Txk, Tyl);                 // event ending segment n
        const float prev = fmaxf(te, fmaxf(Txkm1, Tylm1));  // event starting it
        const float dt   = __fadd_rn(fminf(Tn, tex), -fminf(prev, tex));
        const bool active = (prev < tex_m_eps);
        float w = __fmul_rn(fmaxf(0.0f, dt), wscale);
        w = active ? w : 0.0f;

        const int ii = min(95, max(0, i0 + ((si > 0) ? k : -k)));
        const int jj = min(95, max(0, j0 + ((sj > 0) ? m : -m)));
        int2 e;
        e.x = (ii * NH + jj) << 8;             // BYTE offset into vol (256B rows)
        e.y = __float_as_int(w);
        myRow[n] = e;

        cnt += (int)__popcll(__ballot(active));
    }
    // cap is WAVE-UNIFORM (popc of ballots over EXECUTED rounds) -> SGPRs.
    const int cap = min((cnt + 15) & ~15, CNTMAX);

    // ---------------- gather: quad-row (R10 structure, validated) ----------
    const int r   = lane >> 4;
    const int sub = lane & 15;
    const int subOff = sub << 4;

    const int2* __restrict__ eRow = myRow + r;       // entry n+r at [n]
    const char* __restrict__ vb   = (const char*)vol;

    float4 acc[4] = {{0,0,0,0}, {0,0,0,0}, {0,0,0,0}, {0,0,0,0}};
    for (int n = 0; n < cap; n += 16) {
        const int2 e0 = eRow[n];        // 4-address LDS broadcast (conflict-free)
        const int2 e1 = eRow[n + 4];
        const int2 e2 = eRow[n + 8];
        const int2 e3 = eRow[n + 12];
        const float4 v0 = *(const float4*)(vb + (e0.x + subOff));  // 4 rows/instr
        const float4 v1 = *(const float4*)(vb + (e1.x + subOff));
        const float4 v2 = *(const float4*)(vb + (e2.x + subOff));
        const float4 v3 = *(const float4*)(vb + (e3.x + subOff));
        const float w0 = __int_as_float(e0.y);
        const float w1 = __int_as_float(e1.y);
        const float w2 = __int_as_float(e2.y);
        const float w3 = __int_as_float(e3.y);
        acc[0].x = fmaf(w0, v0.x, acc[0].x); acc[0].y = fmaf(w0, v0.y, acc[0].y);
        acc[0].z = fmaf(w0, v0.z, acc[0].z); acc[0].w = fmaf(w0, v0.w, acc[0].w);
        acc[1].x = fmaf(w1, v1.x, acc[1].x); acc[1].y = fmaf(w1, v1.y, acc[1].y);
        acc[1].z = fmaf(w1, v1.z, acc[1].z); acc[1].w = fmaf(w1, v1.w, acc[1].w);
        acc[2].x = fmaf(w2, v2.x, acc[2].x); acc[2].y = fmaf(w2, v2.y, acc[2].y);
        acc[2].z = fmaf(w2, v2.z, acc[2].z); acc[2].w = fmaf(w2, v2.w, acc[2].w);
        acc[3].x = fmaf(w3, v3.x, acc[3].x); acc[3].y = fmaf(w3, v3.y, acc[3].y);
        acc[3].z = fmaf(w3, v3.z, acc[3].z); acc[3].w = fmaf(w3, v3.w, acc[3].w);
    }

    // ---- R19 DIAGNOSTIC: 3 extra warm gather passes (timing probe only) ----
    // Same addresses at runtime (L2-warm) but formally distinct via opaque
    // zero -> no CSE across passes or against the real gather. Loads consumed
    // by empty asm (no DCE, rule #17). No fmaf: isolates the LDS->VMEM path.
    for (int p = 0; p < 3; ++p) {
        int zz;
        asm volatile("v_mov_b32 %0, 0" : "=v"(zz));    // fresh opaque 0 per pass
        const int so = subOff + zz;
        for (int n = 0; n < cap; n += 16) {
            const int2 e0 = eRow[n];
            const int2 e1 = eRow[n + 4];
            const int2 e2 = eRow[n + 8];
            const int2 e3 = eRow[n + 12];
            const float4 d0 = *(const float4*)(vb + (e0.x + so));
            const float4 d1 = *(const float4*)(vb + (e1.x + so));
            const float4 d2 = *(const float4*)(vb + (e2.x + so));
            const float4 d3 = *(const float4*)(vb + (e3.x + so));
            asm volatile("" :: "v"(d0.x), "v"(d0.y), "v"(d0.z), "v"(d0.w),
                               "v"(d1.x), "v"(d1.y), "v"(d1.z), "v"(d1.w),
                               "v"(d2.x), "v"(d2.y), "v"(d2.z), "v"(d2.w),
                               "v"(d3.x), "v"(d3.y), "v"(d3.z), "v"(d3.w));
        }
    }

    float sx = (acc[0].x + acc[1].x) + (acc[2].x + acc[3].x);
    float sy = (acc[0].y + acc[1].y) + (acc[2].y + acc[3].y);
    float sz = (acc[0].z + acc[1].z) + (acc[2].z + acc[3].z);
    float sw = (acc[0].w + acc[1].w) + (acc[2].w + acc[3].w);

    // reduce across the 4 row groups: lanes {sub, 16+sub, 32+sub, 48+sub}
    sx += __shfl_xor(sx, 16, 64);  sy += __shfl_xor(sy, 16, 64);
    sz += __shfl_xor(sz, 16, 64);  sw += __shfl_xor(sw, 16, 64);
    sx += __shfl_xor(sx, 32, 64);  sy += __shfl_xor(sy, 32, 64);
    sz += __shfl_xor(sz, 32, 64);  sw += __shfl_xor(sw, 32, 64);

    if (lane < 16) {
        float4 res; res.x = sx; res.y = sy; res.z = sz; res.w = sw;
        *(float4*)(out + (u * NA + a) * NV + (sub << 2)) = res;  // 256B coalesced
    }
}

__global__ __launch_bounds__(512, 8)
void siddon_fused(const float* __restrict__ vol, float* __restrict__ out)
{
    __shared__ int2 sEnt[TILE][NENT];  // .x = BYTE offset of vol row, .y = weight bits

    const int tid  = threadIdx.x;
    const int wid  = tid >> 6;         // wave index in block
    const int lane = tid & 63;
    const int bid  = blockIdx.x;

    int2* __restrict__ myRow = &sEnt[wid][0];

    const int ray0 = bid * TILE + wid;             // rays 0..8191
    do_ray(vol, out, myRow, ray0, lane);

    // leftover rays 8192..8639: one per block (bid<448), on a wave chosen so
    // the two extras per CU land on different SIMDs.
    if (bid < NEXTRA && wid == ((bid + (bid >> 8)) & 7)) {
        do_ray(vol, out, myRow, NBLK * TILE + bid, lane);
    }
}

extern "C" void kernel_launch(void* const* d_in, const int* in_sizes, int n_in,
                              void* d_out, int out_size, void* d_ws, size_t ws_size,
                              hipStream_t stream) {
    const float* vol = (const float*)d_in[0];
    float* out = (float*)d_out;
    hipLaunchKernelGGL(siddon_fused, dim3(NBLK), dim3(512), 0, stream, vol, out);
}

// Round 7
// 66.367 us; speedup vs baseline: 1.3549x; 1.3549x over previous
//
#include <hip/hip_runtime.h>
#include <math.h>

// R20: 2-deep software-pipelined gather. R19's diagnostic showed VGPR=24 —
// the regalloc kept only ~1-2 of the 4 gather loads in flight, serializing
// ~200cy L2 latency per load (5.7us per warm pass measured; HBM 3%, LDS
// conflicts 0, VALU 34%, occupancy 53% => pure latency-bound). Fix: named
// cur/next registers, issue next iteration's 4 dwordx4 BEFORE consuming the
// current one (8 float4 + acc[4] = 48 regs in flight <= 64 budget).
// FMA order per accumulator unchanged => bit-identical output vs R17.
//
//   vol: (B=1, C=1, W=96, H=96, D=64) float32 -> vol[(x*96+y)*64+z]
//   out: (B,C,U=96,A=90,V=64) float32 -> out[(u*90+a)*64+v]
namespace {
constexpr int NA = 90, NU = 96, NV = 64, NW = 96, NH = 96, ND = 64;
constexpr int NRAY   = NA * NU;      // 8640
constexpr int NENT   = 256;          // entries per ray (<=4 rounds x 64 lanes)
constexpr int CNTMAX = 208;          // gather cap (valid count <= ~196 structurally)
constexpr int TILE   = 8;            // rays per block = waves per block
constexpr int NBLK   = 1024;         // exactly 4 blocks/CU (32 waves/CU), vgpr<=64
constexpr int NEXTRA = NRAY - NBLK * TILE;  // 448 leftover rays, spread 1-per-block
}

// Compact branch-free f64 sincos (fdlibm kernel polys, |err| ~3e-16).
__device__ inline void sincos_poly(double xd, float* s, float* c)
{
    const double INV_PIO2 = 0.63661977236758134308;
    const double PIO2_HI  = 1.57079632679489655800e+00;
    const double PIO2_LO  = 6.12323399573676603587e-17;
    const double qd = rint(xd * INV_PIO2);            // 0,1,2 for xd in [0, 3.11)
    const double r  = (xd - qd * PIO2_HI) - qd * PIO2_LO;
    const double z  = r * r;
    const double sp = r + (r * z) * (-1.66666666666666324348e-01 + z *
                     ( 8.33333333332248946124e-03 + z *
                     (-1.98412698298579493134e-04 + z *
                     ( 2.75573137070700676789e-06 + z *
                     (-2.50507602534068634195e-08 + z *
                       1.58969099521155010221e-10)))));
    const double cp = 1.0 + z * (-0.5 + z *
                     ( 4.16666666666666019037e-02 + z *
                     (-1.38888888888741095749e-03 + z *
                     ( 2.48015872894767294178e-05 + z *
                     (-2.75573143513906633035e-07 + z *
                     ( 2.08757232129817482790e-09 + z *
                      -1.13596475577881948265e-11))))));
    const int q = (int)qd;
    const double sv = (q == 0) ? sp : ((q == 1) ? cp : -sp);
    const double cv = (q == 0) ? cp : ((q == 1) ? -sp : -cp);
    *s = (float)sv;
    *c = (float)cv;
}

// Wave-uniform scalars -> SGPRs (R16; semantics-preserving, all lanes identical).
__device__ __forceinline__ float rflf(float x) {
    return __int_as_float(__builtin_amdgcn_readfirstlane(__float_as_int(x)));
}
__device__ __forceinline__ int rfli(int x) {
    return __builtin_amdgcn_readfirstlane(x);
}

// One full ray (setup -> trace -> pipelined gather -> out write).
__device__ __forceinline__ void do_ray(const float* __restrict__ vol,
                                       float* __restrict__ out,
                                       int2* __restrict__ myRow,
                                       const int ray, const int lane)
{
    const int a = ray / NU;
    const int u = ray - a * NU;

    const float EPSf = 1e-12f;
    const float INFp = __builtin_inff();
    const float DIAG = 1.41421356237309514547f;

    // ---------------- per-ray setup (wave-uniform) ----------------
    const float ang = (float)a * (float)(3.14159265358979323846 / 90.0);
    float dy, dx;
    sincos_poly((double)ang, &dy, &dx);        // dx = cos, dy = sin (f32-exact)
    const float uu = (float)u - 47.5f;
    const float x0 = __fmul_rn(-uu, dy);
    const float y0 = __fmul_rn( uu, dx);

    const float xmin = -47.5f, xmax = 47.5f;
    const float ymin = -47.5f, ymax = 47.5f;

    float tx0, tx1;
    {
        const bool par = fabsf(dx) < EPSf;
        const float safe = par ? 1.0f : dx;
        const float t0 = __fdiv_rn(xmin - x0, safe);
        const float t1 = __fdiv_rn(xmax - x0, safe);
        const float lo = fminf(t0, t1), hi = fmaxf(t0, t1);
        const bool inside = (x0 >= xmin) && (x0 <= xmax);
        tx0 = par ? (inside ? -INFp : INFp) : lo;
        tx1 = par ? (inside ?  INFp : -INFp) : hi;
    }
    float ty0, ty1;
    {
        const bool par = fabsf(dy) < EPSf;
        const float safe = par ? 1.0f : dy;
        const float t0 = __fdiv_rn(ymin - y0, safe);
        const float t1 = __fdiv_rn(ymax - y0, safe);
        const float lo = fminf(t0, t1), hi = fmaxf(t0, t1);
        const bool inside = (y0 >= ymin) && (y0 <= ymax);
        ty0 = par ? (inside ? -INFp : INFp) : lo;
        ty1 = par ? (inside ?  INFp : -INFp) : hi;
    }

    const float t_entry = fmaxf(tx0, ty0);
    const float t_exit  = fminf(tx1, ty1);
    const bool  alive0  = t_entry < t_exit;
    const float te  = rflf(alive0 ? t_entry : 0.0f);
    const float tex = rflf(alive0 ? t_exit  : 0.0f);

    const float xe = __fadd_rn(x0, __fmul_rn(te, dx));
    const float ye = __fadd_rn(y0, __fmul_rn(te, dy));
    const int i0 = rfli((int)fminf(fmaxf(rintf(__fadd_rn(xe, 47.5f)), 0.0f), 95.0f));
    const int j0 = rfli((int)fminf(fmaxf(rintf(__fadd_rn(ye, 47.5f)), 0.0f), 95.0f));

    const bool okx = fabsf(dx) > EPSf;
    const bool oky = fabsf(dy) > EPSf;
    const float inv_dx = okx ? __fdiv_rn(1.0f, dx) : 0.0f;
    const float inv_dy = oky ? __fdiv_rn(1.0f, dy) : 0.0f;
    const float wscale = rflf(__fdiv_rn(DIAG, fmaxf(fabsf(dx) + fabsf(dy), EPSf)));
    // When !alive0: te=tex=0 => prev >= 0 > tex-eps => inactive automatically.
    const float tex_m_eps = rflf(__fadd_rn(tex, -EPSf));

    // APs of crossing times: Tx_k = Ax + k*px, Ty_m = Ay + m*py (absolute t).
    const float cx = (dx > 0.0f) ? -47.0f : -48.0f;
    const float cy = (dy > 0.0f) ? -47.0f : -48.0f;
    const float Ax = rflf(okx ? __fadd_rn(te, __fmul_rn(((float)i0 + cx) - xe, inv_dx)) : INFp);
    const float Ay = rflf(oky ? __fadd_rn(te, __fmul_rn(((float)j0 + cy) - ye, inv_dy)) : INFp);
    const float px = rflf(okx ? fabsf(inv_dx) : 0.0f);
    const float py = rflf(oky ? fabsf(inv_dy) : 0.0f);
    const int   si = rfli((dx > 0.0f) ? 1 : -1);
    const int   sj = rfli((dy > 0.0f) ? 1 : -1);

    const float inv_pq = rflf(__fdiv_rn(1.0f, px + py));
    const float Cc = rflf(Ay - Ax);

    // ---- R17: closed-form valid-segment count -> variable round count ----
    int nx = 0, ny = 0;
    if (okx) {
        const float Qx = __fdiv_rn(tex_m_eps - Ax, px);
        nx = min(96, max(0, (int)floorf(Qx) + 1));
    }
    if (oky) {
        const float Qy = __fdiv_rn(tex_m_eps - Ay, py);
        ny = min(96, max(0, (int)floorf(Qy) + 1));
    }
    const int nvalid = 1 + nx + ny;                     // <= 193 structurally
    const int rounds = rfli(alive0 ? min(4, (nvalid + 2 + 63) >> 6) : 0);

    // ---------------- lane-parallel trace: `rounds` rounds of 64 entries ----
    int cnt = 0;
    for (int rnd = 0; rnd < rounds; ++rnd) {
        const int n = (rnd << 6) + lane;
        const float nf = (float)n;

        float kf = __fmul_rn(__fmaf_rn(nf, py, Cc), inv_pq);
        kf = fminf(fmaxf(kf, 0.0f), nf);       // also collapses +-INF safely
        int k = (int)rintf(kf);

        // partition fixup: valid iff Tx_{k-1} <= Ty_{n-k} and Ty_{n-k-1} <= Tx_k.
        #pragma unroll
        for (int it = 0; it < 4; ++it) {
            const int m = n - k;
            const float Txk   = __fmaf_rn((float)k, px, Ax);
            const float Txkm1 = (k > 0) ? __fmaf_rn((float)(k - 1), px, Ax) : -INFp;
            const float Tyl   = __fmaf_rn((float)m, py, Ay);
            const float Tylm1 = (m > 0) ? __fmaf_rn((float)(m - 1), py, Ay) : -INFp;
            const bool dec = (Txkm1 > Tyl);
            const bool inc = (!dec) && (Tylm1 > Txk);
            k += inc ? 1 : (dec ? -1 : 0);
        }

        const int m = n - k;
        const float Txk   = __fmaf_rn((float)k, px, Ax);
        const float Txkm1 = (k > 0) ? __fmaf_rn((float)(k - 1), px, Ax) : -INFp;
        const float Tyl   = __fmaf_rn((float)m, py, Ay);
        const float Tylm1 = (m > 0) ? __fmaf_rn((float)(m - 1), py, Ay) : -INFp;

        const float Tn   = fminf(Txk, Tyl);                 // event ending segment n
        const float prev = fmaxf(te, fmaxf(Txkm1, Tylm1));  // event starting it
        const float dt   = __fadd_rn(fminf(Tn, tex), -fminf(prev, tex));
        const bool active = (prev < tex_m_eps);
        float w = __fmul_rn(fmaxf(0.0f, dt), wscale);
        w = active ? w : 0.0f;

        const int ii = min(95, max(0, i0 + ((si > 0) ? k : -k)));
        const int jj = min(95, max(0, j0 + ((sj > 0) ? m : -m)));
        int2 e;
        e.x = (ii * NH + jj) << 8;             // BYTE offset into vol (256B rows)
        e.y = __float_as_int(w);
        myRow[n] = e;

        cnt += (int)__popcll(__ballot(active));
    }
    // cap is WAVE-UNIFORM (popc of ballots over EXECUTED rounds) -> SGPRs.
    const int cap = min((cnt + 15) & ~15, CNTMAX);

    // ---------------- gather: quad-row, 2-deep pipelined (R20) -------------
    // Lane L: row-in-quad r=L>>4, 16B chunk sub=L&15. One dwordx4 per 4
    // entries fetches four 256B vol rows. Each iteration ISSUES the next
    // iteration's 4 loads before CONSUMING the current one's -> 8 float4 in
    // flight, L2 latency overlapped with fmafs instead of serialized.
    const int r   = lane >> 4;
    const int sub = lane & 15;
    const int subOff = sub << 4;

    const int2* __restrict__ eRow = myRow + r;       // entry n+r at [n]
    const char* __restrict__ vb   = (const char*)vol;

    float4 acc[4] = {{0,0,0,0}, {0,0,0,0}, {0,0,0,0}, {0,0,0,0}};
    if (cap > 0) {   // cap >= 16 here (cnt >= 1 whenever any round ran)
        // prologue: iteration 0 entries + loads
        int2 e0 = eRow[0];
        int2 e1 = eRow[4];
        int2 e2 = eRow[8];
        int2 e3 = eRow[12];
        float4 v0 = *(const float4*)(vb + (e0.x + subOff));
        float4 v1 = *(const float4*)(vb + (e1.x + subOff));
        float4 v2 = *(const float4*)(vb + (e2.x + subOff));
        float4 v3 = *(const float4*)(vb + (e3.x + subOff));

        for (int n = 16; n < cap; n += 16) {
            // issue next iteration's loads FIRST (LDS broadcast + 4 dwordx4)
            const int2 f0 = eRow[n];
            const int2 f1 = eRow[n + 4];
            const int2 f2 = eRow[n + 8];
            const int2 f3 = eRow[n + 12];
            const float4 u0 = *(const float4*)(vb + (f0.x + subOff));
            const float4 u1 = *(const float4*)(vb + (f1.x + subOff));
            const float4 u2 = *(const float4*)(vb + (f2.x + subOff));
            const float4 u3 = *(const float4*)(vb + (f3.x + subOff));

            // consume current iteration (same fma order as R17 -> bit-identical)
            const float w0 = __int_as_float(e0.y);
            const float w1 = __int_as_float(e1.y);
            const float w2 = __int_as_float(e2.y);
            const float w3 = __int_as_float(e3.y);
            acc[0].x = fmaf(w0, v0.x, acc[0].x); acc[0].y = fmaf(w0, v0.y, acc[0].y);
            acc[0].z = fmaf(w0, v0.z, acc[0].z); acc[0].w = fmaf(w0, v0.w, acc[0].w);
            acc[1].x = fmaf(w1, v1.x, acc[1].x); acc[1].y = fmaf(w1, v1.y, acc[1].y);
            acc[1].z = fmaf(w1, v1.z, acc[1].z); acc[1].w = fmaf(w1, v1.w, acc[1].w);
            acc[2].x = fmaf(w2, v2.x, acc[2].x); acc[2].y = fmaf(w2, v2.y, acc[2].y);
            acc[2].z = fmaf(w2, v2.z, acc[2].z); acc[2].w = fmaf(w2, v2.w, acc[2].w);
            acc[3].x = fmaf(w3, v3.x, acc[3].x); acc[3].y = fmaf(w3, v3.y, acc[3].y);
            acc[3].z = fmaf(w3, v3.z, acc[3].z); acc[3].w = fmaf(w3, v3.w, acc[3].w);

            // rotate named registers (no runtime-indexed arrays, rule #20)
            e0 = f0; e1 = f1; e2 = f2; e3 = f3;
            v0 = u0; v1 = u1; v2 = u2; v3 = u3;
        }

        // epilogue: consume the last iteration
        const float w0 = __int_as_float(e0.y);
        const float w1 = __int_as_float(e1.y);
        const float w2 = __int_as_float(e2.y);
        const float w3 = __int_as_float(e3.y);
        acc[0].x = fmaf(w0, v0.x, acc[0].x); acc[0].y = fmaf(w0, v0.y, acc[0].y);
        acc[0].z = fmaf(w0, v0.z, acc[0].z); acc[0].w = fmaf(w0, v0.w, acc[0].w);
        acc[1].x = fmaf(w1, v1.x, acc[1].x); acc[1].y = fmaf(w1, v1.y, acc[1].y);
        acc[1].z = fmaf(w1, v1.z, acc[1].z); acc[1].w = fmaf(w1, v1.w, acc[1].w);
        acc[2].x = fmaf(w2, v2.x, acc[2].x); acc[2].y = fmaf(w2, v2.y, acc[2].y);
        acc[2].z = fmaf(w2, v2.z, acc[2].z); acc[2].w = fmaf(w2, v2.w, acc[2].w);
        acc[3].x = fmaf(w3, v3.x, acc[3].x); acc[3].y = fmaf(w3, v3.y, acc[3].y);
        acc[3].z = fmaf(w3, v3.z, acc[3].z); acc[3].w = fmaf(w3, v3.w, acc[3].w);
    }

    float sx = (acc[0].x + acc[1].x) + (acc[2].x + acc[3].x);
    float sy = (acc[0].y + acc[1].y) + (acc[2].y + acc[3].y);
    float sz = (acc[0].z + acc[1].z) + (acc[2].z + acc[3].z);
    float sw = (acc[0].w + acc[1].w) + (acc[2].w + acc[3].w);

    // reduce across the 4 row groups: lanes {sub, 16+sub, 32+sub, 48+sub}
    sx += __shfl_xor(sx, 16, 64);  sy += __shfl_xor(sy, 16, 64);
    sz += __shfl_xor(sz, 16, 64);  sw += __shfl_xor(sw, 16, 64);
    sx += __shfl_xor(sx, 32, 64);  sy += __shfl_xor(sy, 32, 64);
    sz += __shfl_xor(sz, 32, 64);  sw += __shfl_xor(sw, 32, 64);

    if (lane < 16) {
        float4 res; res.x = sx; res.y = sy; res.z = sz; res.w = sw;
        *(float4*)(out + (u * NA + a) * NV + (sub << 2)) = res;  // 256B coalesced
    }
}

__global__ __launch_bounds__(512, 8)
void siddon_fused(const float* __restrict__ vol, float* __restrict__ out)
{
    __shared__ int2 sEnt[TILE][NENT];  // .x = BYTE offset of vol row, .y = weight bits

    const int tid  = threadIdx.x;
    const int wid  = tid >> 6;         // wave index in block
    const int lane = tid & 63;
    const int bid  = blockIdx.x;

    int2* __restrict__ myRow = &sEnt[wid][0];

    const int ray0 = bid * TILE + wid;             // rays 0..8191
    do_ray(vol, out, myRow, ray0, lane);

    // leftover rays 8192..8639: one per block (bid<448), on a wave chosen so
    // the two extras per CU land on different SIMDs.
    if (bid < NEXTRA && wid == ((bid + (bid >> 8)) & 7)) {
        do_ray(vol, out, myRow, NBLK * TILE + bid, lane);
    }
}

extern "C" void kernel_launch(void* const* d_in, const int* in_sizes, int n_in,
                              void* d_out, int out_size, void* d_ws, size_t ws_size,
                              hipStream_t stream) {
    const float* vol = (const float*)d_in[0];
    float* out = (float*)d_out;
    hipLaunchKernelGGL(siddon_fused, dim3(NBLK), dim3(512), 0, stream, vol, out);
}